// Round 8
// baseline (2008.632 us; speedup 1.0000x reference)
//
#include <hip/hip_runtime.h>

// Problem constants (from reference): Q=512 states, S=64 symbols, B=64, T=256.
#define QN 512
#define SN 64
#define BN 64
#define TN 256
#define GS 8   // row/col-split: blocks per batch (grid = GS*BN = 512 = 2 blocks/CU)

typedef unsigned long long ull;

// ---- int8 dot4 (v_dot4_i32_i8) with software fallback ----
#if defined(__has_builtin)
#if __has_builtin(__builtin_amdgcn_sdot4)
#define SDOT4(a, b, c) __builtin_amdgcn_sdot4((a), (b), (c), false)
#endif
#endif
#ifndef SDOT4
static __device__ __forceinline__ int sdot4_sw(int a, int b, int c) {
    c += (int)(signed char)(a)       * (int)(signed char)(b);
    c += (int)(signed char)(a >> 8)  * (int)(signed char)(b >> 8);
    c += (int)(signed char)(a >> 16) * (int)(signed char)(b >> 16);
    c += (int)(signed char)(a >> 24) * (int)(signed char)(b >> 24);
    return c;
}
#define SDOT4(a, b, c) sdot4_sw((a), (b), (c))
#endif

// signed-nibble unpack: bytes of (x & 0x0F..) are in [0,15]; ^8 then -8 per
// byte maps to [-8,7] two's-complement bytes; no cross-byte borrow possible.
#define NIB_LO(x) ((((x) & 0x0F0F0F0F) ^ 0x08080808) - 0x08080808)
#define NIB_HI(x) (((((x) >> 4) & 0x0F0F0F0F) ^ 0x08080808) - 0x08080808)

static __device__ __forceinline__ float wave_sum(float v) {
    #pragma unroll
    for (int o = 32; o > 0; o >>= 1) v += __shfl_xor(v, o, 64);
    return v;
}
static __device__ __forceinline__ float wave_max(float v) {
    #pragma unroll
    for (int o = 32; o > 0; o >>= 1) v = fmaxf(v, __shfl_xor(v, o, 64));
    return v;
}

// Barrier with LDS-only drain: waits lgkmcnt(0) but leaves global loads in
// flight (vmcnt untouched) so cross-step register prefetch survives the
// barrier. imm encoding (gfx9/CDNA): vm[3:0]=0xF, exp[6:4]=7, lgkm[11:8]=0,
// vm[15:14]=3 -> 0xC07F.
static __device__ __forceinline__ void barrier_lds(void) {
    __builtin_amdgcn_s_waitcnt(0xC07F);
    __builtin_amdgcn_s_barrier();
}

// Exchange transport: agent-scope atomics (sc0 sc1 -> LLC write-through /
// LLC read). PROVEN rounds 1/3/4/7. Round-2 post-mortem: flat/lgkm polling
// is unsound (lgkm decrement does not guarantee data return). Round-6
// post-mortem: sc0-only L2 "fast path" is UNSOUND cross-XCD (clean stale L2
// lines, no invalidation; a t=0 probe cannot certify t>0). LLC only.
static __device__ __forceinline__ void st_tag(ull* p, ull v) {
    __hip_atomic_store(p, v, __ATOMIC_RELAXED, __HIP_MEMORY_SCOPE_AGENT);
}
static __device__ __forceinline__ ull ld_tag(const ull* p) {
    return __hip_atomic_load(p, __ATOMIC_RELAXED, __HIP_MEMORY_SCOPE_AGENT);
}

#define POLL_GUARD (1 << 20)   // turns any protocol error into a visible
                               // wrong answer instead of a hang

// ---- Kernel A: per-symbol bound of |E| = |exp(A) - 1/Q| via min/max of A ----
__global__ __launch_bounds__(256) void k_minmax(const float* __restrict__ A,
                                                unsigned* __restrict__ smax) {
    const int s  = blockIdx.x >> 3;
    const int i0 = (blockIdx.x & 7) * 64;
    const int tl = threadIdx.x & 127;
    const int rh = threadIdx.x >> 7;
    float mx = -1e30f, mn = 1e30f;
    for (int ro = 0; ro < 64; ro += 2) {
        const int i = i0 + ro + rh;
        float4 a4 = ((const float4*)A)[(size_t)(i * 64 + s) * 128 + tl];
        mx = fmaxf(mx, fmaxf(fmaxf(a4.x, a4.y), fmaxf(a4.z, a4.w)));
        mn = fminf(mn, fminf(fminf(a4.x, a4.y), fminf(a4.z, a4.w)));
    }
    mx = wave_max(mx);
    mn = -wave_max(-mn);
    if ((threadIdx.x & 63) == 0) {
        const float c = 1.0f / 512.0f;
        float se = fmaxf(expf(mx) - c, c - expf(mn));
        atomicMax(&smax[s], __float_as_uint(se));
    }
}

// ---- Kernel B: int4 nibbles + EXACT fp32 per-chunk (64-col) row sums ----
// Epk (int4-vector units): (s*16 + j32)*512 + i covers the 32-column block
// j = 32*j32 + {0..31} at output row i: word w's LO nibbles are cols
// 32*j32+4w+{0..3}, HI nibbles are cols 32*j32+16+4w+{0..3}.
// CS[s][g][i] = sum_{j in 64-col chunk g} E[i,j] (exact fp32): kills the
// E-quant mean-term in the column-split step. ES[s][i] = sum_g CS.
__global__ __launch_bounds__(256) void k_quant(const float* __restrict__ A,
                                               const unsigned* __restrict__ smax,
                                               int* __restrict__ Epk,
                                               float* __restrict__ ES,
                                               float* __restrict__ CS) {
    __shared__ int tile[64][129];     // int8 bytes of e4 values in [-7,7]
    __shared__ float fsumC[64][GS];   // per-row per-chunk exact sums
    const int s  = blockIdx.x >> 3;
    const int i0 = (blockIdx.x & 7) * 64;
    const float se  = __uint_as_float(smax[s]);
    const float inv = se > 0.0f ? 7.0f / se : 0.0f;   // int4 grid: se4 = se/7
    const float c = 1.0f / 512.0f;
    const int tl = threadIdx.x & 127;
    const int rh = threadIdx.x >> 7;
    if (threadIdx.x < 256) {
        ((float*)fsumC)[threadIdx.x] = 0.0f;
        ((float*)fsumC)[256 + threadIdx.x] = 0.0f;
    }
    __syncthreads();
    for (int ro = 0; ro < 64; ro += 2) {
        const int r = ro + rh;
        const int i = i0 + r;
        float4 a4 = ((const float4*)A)[(size_t)(i * 64 + s) * 128 + tl];
        const float e0 = expf(a4.x) - c, e1 = expf(a4.y) - c;
        const float e2 = expf(a4.z) - c, e3 = expf(a4.w) - c;
        int q0 = (int)rintf(fminf(fmaxf(e0 * inv, -7.0f), 7.0f));
        int q1 = (int)rintf(fminf(fmaxf(e1 * inv, -7.0f), 7.0f));
        int q2 = (int)rintf(fminf(fmaxf(e2 * inv, -7.0f), 7.0f));
        int q3 = (int)rintf(fminf(fmaxf(e3 * inv, -7.0f), 7.0f));
        tile[r][tl] = (q0 & 255) | ((q1 & 255) << 8) | ((q2 & 255) << 16) | ((q3 & 255) << 24);
        // exact fp32 per-chunk rowsum: aligned 16-lane group = one 64-col chunk
        float gs = e0 + e1 + e2 + e3;
        #pragma unroll
        for (int o = 8; o > 0; o >>= 1) gs += __shfl_xor(gs, o, 64);
        if ((threadIdx.x & 15) == 0) atomicAdd(&fsumC[r][tl >> 4], gs);
    }
    __syncthreads();
    if (threadIdx.x < 256) {
        #pragma unroll
        for (int h = 0; h < 2; ++h) {
            const int idx = threadIdx.x + 256 * h;
            const int r = idx >> 3, gg = idx & 7;
            CS[((size_t)(s * GS + gg) << 9) + i0 + r] = fsumC[r][gg];
        }
    }
    if (threadIdx.x < 64) {
        const int r = threadIdx.x;
        float es = 0.0f;
        #pragma unroll
        for (int gg = 0; gg < GS; ++gg) es += fsumC[r][gg];
        ES[(s << 9) + i0 + r] = es;
    }
    // pack nibble pairs (col j with col j+16 of the same 32-block) and write
    const int il = threadIdx.x & 63;
    const int jg = threadIdx.x >> 6;          // 0..3
    for (int jo = 0; jo < 4; ++jo) {
        const int j32 = jg * 4 + jo;
        int4 v;
        v.x = (tile[il][8 * j32 + 0] & 0x0F0F0F0F) | ((tile[il][8 * j32 + 4] & 0x0F0F0F0F) << 4);
        v.y = (tile[il][8 * j32 + 1] & 0x0F0F0F0F) | ((tile[il][8 * j32 + 5] & 0x0F0F0F0F) << 4);
        v.z = (tile[il][8 * j32 + 2] & 0x0F0F0F0F) | ((tile[il][8 * j32 + 6] & 0x0F0F0F0F) << 4);
        v.w = (tile[il][8 * j32 + 3] & 0x0F0F0F0F) | ((tile[il][8 * j32 + 7] & 0x0F0F0F0F) << 4);
        ((int4*)Epk)[((size_t)(s * 16 + j32) * 512) + i0 + il] = v;
    }
}

// ---- Main kernel: GS=8 (2 blocks/CU), 2 matvec steps per ONE exchange ----
// Super-step k: s_R = xs[2k] ROW-split (block g computes its 64 rows of
// alpha_{2k+1}, kept LOCAL), s_C = xs[2k+1] COLUMN-split (block g quantizes
// its own 64-row chunk vs the known mean mu_{2k}, computes the full-512-row
// partial y_g; consumers sum the 8 partials). Occupancy doubled vs round 7:
// __launch_bounds__(1024,8) + grid 512 = exact CU capacity -> all blocks
// co-resident (poll protocol deadlock-free), 2 blocks/CU hide each other's
// vmcnt/exchange stalls. Transport: LLC tagged words, tag = k+1, '>=' + memset
// (round-4/7 proven). Producer lead bounded to 1 super-step -> parity
// double-buffer is overwrite-safe.
__global__ __launch_bounds__(1024, 8) void k_fsa(const int* __restrict__ Epk,
                                                 const float* __restrict__ ES,
                                                 const float* __restrict__ CS,
                                                 const unsigned* __restrict__ smax,
                                                 const float* __restrict__ init_w,
                                                 const float* __restrict__ fin_w,
                                                 const int* __restrict__ xs,
                                                 ull* __restrict__ ax,  // [2][BN][GS][QN] tagged y
                                                 float* __restrict__ out) {
    __shared__ __align__(16) int qa[2][QN / 4];    // int8 alpha (full), parity
    __shared__ __align__(16) int qloc[16];         // int8 own-chunk quant (64 B)
    __shared__ int   xs_l[TN];
    __shared__ float wsum[8];                      // sync-wave partials (m)
    __shared__ float sws[8];                       // compute-wave partials (S_g)
    __shared__ float se_l[SN];
    __shared__ float mb[2];                        // block sum m, parity

    const int t    = threadIdx.x;
    const int b    = blockIdx.x & (BN - 1);   // blockIdx = g*64 + b
    const int g    = blockIdx.x >> 6;         // 0..7
    const int lane = t & 63, wave = t >> 6;
    const int tr   = t & 7;                   // phase R: col chunk (64 cols)
    const int lr   = t >> 3;                  // phase R: local row 0..63
    const int irow = (g << 6) + lr;           // phase R: owned output row
    const int u    = t - 512;                 // sync: owned alpha index

    if (t < TN) xs_l[t] = xs[b * TN + t];
    if (t < SN) se_l[t] = __uint_as_float(smax[t]) * (0.125f / 889.0f); // Kq/(127*7)

    const float c  = 1.0f / 512.0f;
    const float Kq = 0.125f;

    const int4* __restrict__ Epb = (const int4*)Epk;
    int4 eR[2], eC[2];
    float ESv = 0.0f, CSv = 0.0f;
    float av = 0.0f;   // sync: gathered alpha value

    if (t < 512) {
        // prefetch both phases of super-step 0 (symbols straight from global)
        const int s0 = xs[b * TN], s1 = xs[b * TN + 1];
        const int4* EpR = Epb + (size_t)(s0 * 16 + tr * 2) * 512 + irow;
        const int4* EpC = Epb + (size_t)(s1 * 16 + g * 2) * 512 + t;
        #pragma unroll
        for (int k = 0; k < 2; ++k) { eR[k] = EpR[(size_t)k * 512]; eC[k] = EpC[(size_t)k * 512]; }
        if (tr == 0) ESv = ES[(s0 << 9) + irow];
        CSv = CS[((size_t)(s1 * GS + g) << 9) + t];
    } else {
        // initial alpha: one element per sync thread, computed redundantly
        av = expf(init_w[u]);
        float ws = wave_sum(av);
        if (lane == 0) wsum[wave - 8] = ws;
    }
    barrier_lds();
    if (t >= 512) {
        float m0 = 0.0f;
        #pragma unroll
        for (int w = 0; w < 8; ++w) m0 += wsum[w];
        const float mu     = m0 * (1.0f / 512.0f);
        const float inv_sa = 127.0f / (Kq * mu);
        const int q = (int)rintf(fminf(fmaxf((av - mu) * inv_sa, -127.0f), 127.0f));
        ((char*)qa)[u] = (char)q;             // parity-0 buffer, byte u
        if (u == 0) mb[0] = m0;
    }
    barrier_lds();

    for (int k = 0; k < TN / 2; ++k) {
        const int par = k & 1;
        float mu = 0.0f;
        if (t < 512) {
            const int sR  = xs_l[2 * k];
            const int sRn = xs_l[(2 * k + 2) & (TN - 1)];   // wraps: dummy at end
            const float mm = mb[par];
            mu = mm * (1.0f / 512.0f);
            // ---- phase R: rows [64g,64g+64) of alpha_{2k+1} ----
            const int4* qp   = (const int4*)qa[par];
            const int4* EpRn = Epb + (size_t)(sRn * 16 + tr * 2) * 512 + irow;
            int a0 = 0, a1 = 0, a2 = 0, a3 = 0;
            #pragma unroll
            for (int k4 = 0; k4 < 2; ++k4) {
                const int4 E4 = eR[k4];
                eR[k4] = EpRn[(size_t)k4 * 512];
                const int4 qlo = qp[2 * (2 * tr + k4) + 0];
                const int4 qhi = qp[2 * (2 * tr + k4) + 1];
                a0 = SDOT4(NIB_LO(E4.x), qlo.x, a0);
                a1 = SDOT4(NIB_HI(E4.x), qhi.x, a1);
                a2 = SDOT4(NIB_LO(E4.y), qlo.y, a2);
                a3 = SDOT4(NIB_HI(E4.y), qhi.y, a3);
                a0 = SDOT4(NIB_LO(E4.z), qlo.z, a0);
                a1 = SDOT4(NIB_HI(E4.z), qhi.z, a1);
                a2 = SDOT4(NIB_LO(E4.w), qlo.w, a2);
                a3 = SDOT4(NIB_HI(E4.w), qhi.w, a3);
            }
            __builtin_amdgcn_sched_barrier(0);   // pin eR re-issue before the rest
            int acc = (a0 + a1) + (a2 + a3);
            acc += __shfl_xor(acc, 1, 64);       // reduce over tr (lane bits 0..2)
            acc += __shfl_xor(acc, 2, 64);
            acc += __shfl_xor(acc, 4, 64);
            float outv = 0.0f;
            if (tr == 0) {
                outv = c * mm + mu * (ESv + se_l[sR] * (float)acc);
                ESv = ES[(sRn << 9) + irow];     // prefetch next ES
                // quantize own chunk vs mu_{2k} (deviation ~0.2% mu << Kq=12.5%)
                const float inv_sa = 127.0f / (Kq * mu);
                const int q8 = (int)rintf(fminf(fmaxf((outv - mu) * inv_sa, -127.0f), 127.0f));
                ((char*)qloc)[lr] = (char)q8;
            }
            float ws = wave_sum(outv);           // S_g partial (non-tr0 lanes add 0)
            if (lane == 0) sws[wave] = ws;
        }
        barrier_lds();   // A: qloc + sws visible (intra-block only -- no exchange!)

        if (t < 512) {
            const int sC  = xs_l[2 * k + 1];
            const int sCn = xs_l[(2 * k + 3) & (TN - 1)];
            float Sg = 0.0f;
            #pragma unroll
            for (int w = 0; w < 8; ++w) Sg += sws[w];
            // ---- phase C: full-512-row partial over 64-col chunk g ----
            const int4* qc   = (const int4*)qloc;
            const int4* EpCn = Epb + (size_t)(sCn * 16 + g * 2) * 512 + t;
            int a0 = 0, a1 = 0, a2 = 0, a3 = 0;
            #pragma unroll
            for (int k4 = 0; k4 < 2; ++k4) {
                const int4 E4 = eC[k4];
                eC[k4] = EpCn[(size_t)k4 * 512];
                const int4 ql = qc[2 * k4 + 0];   // local cols 32k4+4w+{0..3}
                const int4 qh = qc[2 * k4 + 1];   // local cols 32k4+16+4w+{0..3}
                a0 = SDOT4(NIB_LO(E4.x), ql.x, a0);
                a1 = SDOT4(NIB_HI(E4.x), qh.x, a1);
                a2 = SDOT4(NIB_LO(E4.y), ql.y, a2);
                a3 = SDOT4(NIB_HI(E4.y), qh.y, a3);
                a0 = SDOT4(NIB_LO(E4.z), ql.z, a0);
                a1 = SDOT4(NIB_HI(E4.z), qh.z, a1);
                a2 = SDOT4(NIB_LO(E4.w), ql.w, a2);
                a3 = SDOT4(NIB_HI(E4.w), qh.w, a3);
            }
            __builtin_amdgcn_sched_barrier(0);
            const int accC = (a0 + a1) + (a2 + a3);
            // y_g[i] = c*S_g + mu*(CS_g[i] + se*acc)  (exact mean terms)
            const float y = c * Sg + mu * (CSv + se_l[sC] * (float)accC);
            CSv = CS[((size_t)(sCn * GS + g) << 9) + t];   // prefetch next CS
            st_tag(ax + ((size_t)((par ^ 1) * BN + b) * GS + g) * QN + t,
                   ((ull)(unsigned)(k + 1) << 32) | (ull)__float_as_uint(y));
        } else {
            // gather: poll the 8 sibling partials for own row u, sum them
            const unsigned want = (unsigned)(k + 1);
            const ull* ap = ax + (size_t)((par ^ 1) * BN + b) * GS * QN + u;
            ull w0 = ld_tag(ap + 0 * QN), w1 = ld_tag(ap + 1 * QN);
            ull w2 = ld_tag(ap + 2 * QN), w3 = ld_tag(ap + 3 * QN);
            ull w4 = ld_tag(ap + 4 * QN), w5 = ld_tag(ap + 5 * QN);
            ull w6 = ld_tag(ap + 6 * QN), w7 = ld_tag(ap + 7 * QN);
            int gd = 0;
            while ((((unsigned)(w0 >> 32) < want) | ((unsigned)(w1 >> 32) < want) |
                    ((unsigned)(w2 >> 32) < want) | ((unsigned)(w3 >> 32) < want) |
                    ((unsigned)(w4 >> 32) < want) | ((unsigned)(w5 >> 32) < want) |
                    ((unsigned)(w6 >> 32) < want) | ((unsigned)(w7 >> 32) < want)) &&
                   ++gd < POLL_GUARD) {
                __builtin_amdgcn_s_sleep(1);
                w0 = ld_tag(ap + 0 * QN); w1 = ld_tag(ap + 1 * QN);
                w2 = ld_tag(ap + 2 * QN); w3 = ld_tag(ap + 3 * QN);
                w4 = ld_tag(ap + 4 * QN); w5 = ld_tag(ap + 5 * QN);
                w6 = ld_tag(ap + 6 * QN); w7 = ld_tag(ap + 7 * QN);
            }
            // fixed order -> bitwise identical across all blocks
            av = ((__uint_as_float((unsigned)w0) + __uint_as_float((unsigned)w1)) +
                  (__uint_as_float((unsigned)w2) + __uint_as_float((unsigned)w3))) +
                 ((__uint_as_float((unsigned)w4) + __uint_as_float((unsigned)w5)) +
                  (__uint_as_float((unsigned)w6) + __uint_as_float((unsigned)w7)));
            float ws = wave_sum(av);
            if (lane == 0) wsum[wave - 8] = ws;
        }
        barrier_lds();   // 1: wsum visible

        if (t >= 512) {
            float m = 0.0f;
            #pragma unroll
            for (int w = 0; w < 8; ++w) m += wsum[w];    // same tree in all blocks
            const float mu2    = m * (1.0f / 512.0f);
            const float inv_sa = 127.0f / (Kq * mu2);
            const int q = (int)rintf(fminf(fmaxf((av - mu2) * inv_sa, -127.0f), 127.0f));
            ((char*)qa)[(par ^ 1) * QN + u] = (char)q;
            if (u == 0) mb[par ^ 1] = m;
        }
        barrier_lds();   // 2: qa[par^1] + mb[par^1] ready for next super-step
    }

    // finalize: sync threads hold gathered final alpha (tag 128) in av
    {
        float v = 0.0f;
        if (t >= 512) {
            v = av * expf(fin_w[u]);
            float ws = wave_sum(v);
            if (lane == 0) wsum[wave - 8] = ws;
        }
        barrier_lds();
        if (g == 0 && t == 512) {
            float tot = 0.0f;
            #pragma unroll
            for (int w = 0; w < 8; ++w) tot += wsum[w];
            out[b] = logf(tot);
        }
    }
}

extern "C" void kernel_launch(void* const* d_in, const int* in_sizes, int n_in,
                              void* d_out, int out_size, void* d_ws, size_t ws_size,
                              hipStream_t stream) {
    const float* A      = (const float*)d_in[0];   // (Q, S, Q) fp32 log-weights
    const float* init_w = (const float*)d_in[1];   // (Q,)
    const float* fin_w  = (const float*)d_in[2];   // (Q,)
    const int*   xs     = (const int*)d_in[3];     // (B, T) int32
    float* out = (float*)d_out;                    // (B,) fp32

    char* ws = (char*)d_ws;
    int*      Epk  = (int*)ws;                                         // 8 MiB (int4 nibbles)
    float*    ES   = (float*)(ws + (8u << 20));                        // 128 KiB
    float*    CS   = (float*)(ws + (8u << 20) + (128u << 10));         // 1 MiB
    unsigned* smax = (unsigned*)(ws + (9u << 20) + (128u << 10));      // 1 KiB slot
    ull*      ax   = (ull*)(ws + (9u << 20) + (129u << 10));           // 4 MiB

    // tags reset every launch (round-4/7 proven protocol: LLC write-through
    // transport + memset + 'tag >= want' compare)
    hipMemsetAsync(smax, 0, (1u << 10) + (4u << 20), stream);
    k_minmax<<<512, 256, 0, stream>>>(A, smax);
    k_quant<<<512, 256, 0, stream>>>(A, smax, Epk, ES, CS);
    k_fsa<<<GS * BN, 1024, 0, stream>>>(Epk, ES, CS, smax, init_w, fin_w, xs, ax, out);
}

// Round 9
// 828.699 us; speedup vs baseline: 2.4238x; 2.4238x over previous
//
#include <hip/hip_runtime.h>

// Problem constants (from reference): Q=512 states, S=64 symbols, B=64, T=256.
#define QN 512
#define SN 64
#define BN 64
#define TN 256
#define GS 4     // row-split: blocks per batch (grid = GS*BN = 256 blocks -> 1/CU)
#define AXW 164  // exchange words per (parity,batch) row: 128 alpha + 32 S + 4 F

typedef unsigned long long ull;

// ---- int8 dot4 (v_dot4_i32_i8) with software fallback ----
#if defined(__has_builtin)
#if __has_builtin(__builtin_amdgcn_sdot4)
#define SDOT4(a, b, c) __builtin_amdgcn_sdot4((a), (b), (c), false)
#endif
#endif
#ifndef SDOT4
static __device__ __forceinline__ int sdot4_sw(int a, int b, int c) {
    c += (int)(signed char)(a)       * (int)(signed char)(b);
    c += (int)(signed char)(a >> 8)  * (int)(signed char)(b >> 8);
    c += (int)(signed char)(a >> 16) * (int)(signed char)(b >> 16);
    c += (int)(signed char)(a >> 24) * (int)(signed char)(b >> 24);
    return c;
}
#define SDOT4(a, b, c) sdot4_sw((a), (b), (c))
#endif

// signed-nibble unpack: bytes of (x & 0x0F..) are in [0,15]; ^8 then -8 per
// byte maps to [-8,7] two's-complement bytes; no cross-byte borrow possible.
#define NIB_LO(x) ((((x) & 0x0F0F0F0F) ^ 0x08080808) - 0x08080808)
#define NIB_HI(x) (((((x) >> 4) & 0x0F0F0F0F) ^ 0x08080808) - 0x08080808)

static __device__ __forceinline__ float wave_sum(float v) {
    #pragma unroll
    for (int o = 32; o > 0; o >>= 1) v += __shfl_xor(v, o, 64);
    return v;
}
static __device__ __forceinline__ float wave_max(float v) {
    #pragma unroll
    for (int o = 32; o > 0; o >>= 1) v = fmaxf(v, __shfl_xor(v, o, 64));
    return v;
}

// Barrier with LDS-only drain: waits lgkmcnt(0) but leaves global loads in
// flight (vmcnt untouched) so cross-step register prefetch survives the
// barrier. imm encoding (gfx9/CDNA): vm[3:0]=0xF, exp[6:4]=7, lgkm[11:8]=0,
// vm[15:14]=3 -> 0xC07F.
static __device__ __forceinline__ void barrier_lds(void) {
    __builtin_amdgcn_s_waitcnt(0xC07F);
    __builtin_amdgcn_s_barrier();
}

// Exchange transport: agent-scope atomics (sc0 sc1). PROVEN rounds 1/3/4/7.
// Round-8 lesson: this traffic is HBM-backed (WRITE_SIZE matched the tagged
// stores exactly) -- so exchange VOLUME is the cost driver; keep it minimal.
// Round-2: flat/lgkm polling unsound. Round-6: sc0-only L2 path unsound
// cross-XCD (clean stale lines, no invalidation).
static __device__ __forceinline__ void st_tag(ull* p, ull v) {
    __hip_atomic_store(p, v, __ATOMIC_RELAXED, __HIP_MEMORY_SCOPE_AGENT);
}
static __device__ __forceinline__ ull ld_tag(const ull* p) {
    return __hip_atomic_load(p, __ATOMIC_RELAXED, __HIP_MEMORY_SCOPE_AGENT);
}

#define POLL_GUARD (1 << 20)   // protocol error -> visible wrong answer, not hang

// ---- Kernel A: per-symbol bound of |E| = |exp(A) - 1/Q| via min/max of A ----
__global__ __launch_bounds__(256) void k_minmax(const float* __restrict__ A,
                                                unsigned* __restrict__ smax) {
    const int s  = blockIdx.x >> 3;
    const int i0 = (blockIdx.x & 7) * 64;
    const int tl = threadIdx.x & 127;
    const int rh = threadIdx.x >> 7;
    float mx = -1e30f, mn = 1e30f;
    for (int ro = 0; ro < 64; ro += 2) {
        const int i = i0 + ro + rh;
        float4 a4 = ((const float4*)A)[(size_t)(i * 64 + s) * 128 + tl];
        mx = fmaxf(mx, fmaxf(fmaxf(a4.x, a4.y), fmaxf(a4.z, a4.w)));
        mn = fminf(mn, fminf(fminf(a4.x, a4.y), fminf(a4.z, a4.w)));
    }
    mx = wave_max(mx);
    mn = -wave_max(-mn);
    if ((threadIdx.x & 63) == 0) {
        const float c = 1.0f / 512.0f;
        float se = fmaxf(expf(mx) - c, c - expf(mn));
        atomicMax(&smax[s], __float_as_uint(se));
    }
}

// ---- Kernel B: quantize E to int4 nibbles + EXACT fp32 rowsums (round 4) ----
__global__ __launch_bounds__(256) void k_quant(const float* __restrict__ A,
                                               const unsigned* __restrict__ smax,
                                               int* __restrict__ Epk,
                                               float* __restrict__ ES) {
    __shared__ int tile[64][129];   // int8 bytes of e4 values in [-7,7]
    __shared__ float fsum[64];
    const int s  = blockIdx.x >> 3;
    const int i0 = (blockIdx.x & 7) * 64;
    const float se  = __uint_as_float(smax[s]);
    const float inv = se > 0.0f ? 7.0f / se : 0.0f;   // int4 grid: se4 = se/7
    const float c = 1.0f / 512.0f;
    const int tl = threadIdx.x & 127;
    const int rh = threadIdx.x >> 7;
    if (threadIdx.x < 64) fsum[threadIdx.x] = 0.0f;
    __syncthreads();
    for (int ro = 0; ro < 64; ro += 2) {
        const int r = ro + rh;
        const int i = i0 + r;
        float4 a4 = ((const float4*)A)[(size_t)(i * 64 + s) * 128 + tl];
        const float e0 = expf(a4.x) - c, e1 = expf(a4.y) - c;
        const float e2 = expf(a4.z) - c, e3 = expf(a4.w) - c;
        int q0 = (int)rintf(fminf(fmaxf(e0 * inv, -7.0f), 7.0f));
        int q1 = (int)rintf(fminf(fmaxf(e1 * inv, -7.0f), 7.0f));
        int q2 = (int)rintf(fminf(fmaxf(e2 * inv, -7.0f), 7.0f));
        int q3 = (int)rintf(fminf(fmaxf(e3 * inv, -7.0f), 7.0f));
        tile[r][tl] = (q0 & 255) | ((q1 & 255) << 8) | ((q2 & 255) << 16) | ((q3 & 255) << 24);
        float ws = wave_sum(e0 + e1 + e2 + e3);
        if ((threadIdx.x & 63) == 0) atomicAdd(&fsum[r], ws);
    }
    __syncthreads();
    if (threadIdx.x < 64) ES[(s << 9) + i0 + threadIdx.x] = fsum[threadIdx.x];
    const int il = threadIdx.x & 63;
    const int jg = threadIdx.x >> 6;          // 0..3
    for (int jo = 0; jo < 4; ++jo) {
        const int j32 = jg * 4 + jo;
        int4 v;
        v.x = (tile[il][8 * j32 + 0] & 0x0F0F0F0F) | ((tile[il][8 * j32 + 4] & 0x0F0F0F0F) << 4);
        v.y = (tile[il][8 * j32 + 1] & 0x0F0F0F0F) | ((tile[il][8 * j32 + 5] & 0x0F0F0F0F) << 4);
        v.z = (tile[il][8 * j32 + 2] & 0x0F0F0F0F) | ((tile[il][8 * j32 + 6] & 0x0F0F0F0F) << 4);
        v.w = (tile[il][8 * j32 + 3] & 0x0F0F0F0F) | ((tile[il][8 * j32 + 7] & 0x0F0F0F0F) << 4);
        ((int4*)Epk)[((size_t)(s * 16 + j32) * 512) + i0 + il] = v;
    }
}

// ---- Main kernel: producer-quantized THIN exchange (40 words/block/step) ----
// Compute thread t<512: row irow = g*128 + (t>>2), col-chunk tr = t&3.
// Producers quantize alpha_{t+1} vs beta_{t+1} = mu_t (KNOWN at production --
// r7-phase-C-proven trick), pack 4 rows/word via 2 shuffles, publish 32 alpha
// words + 8 per-wave exact fp32 partial-sum words. Consumers (sync threads
// u<160, vmcnt-clean waves) poll 1 word each and COPY payload into qa /
// sws -- no consumer requantization, one barrier per step. m is recomputed by
// every thread from sws[par] in fixed order (broadcast reads).
// Tags: step+1, '>=' + memset (proven). Producer lead bounded to 1 step ->
// parity buffers (qa, sws) are overwrite-safe. 256 blocks co-resident.
__global__ __launch_bounds__(1024) void k_fsa(const int* __restrict__ Epk,
                                              const float* __restrict__ ES,
                                              const unsigned* __restrict__ smax,
                                              const float* __restrict__ init_w,
                                              const float* __restrict__ fin_w,
                                              const int* __restrict__ xs,
                                              ull* __restrict__ ax,   // [2][BN][AXW] tagged words
                                              float* __restrict__ out) {
    __shared__ __align__(16) int qa[2][QN / 4];   // int8 alpha, parity buffers
    __shared__ int   xs_l[TN];
    __shared__ float sws[2][32];                  // per-(g,wave) exact partials
    __shared__ float se_l[SN];

    const int t    = threadIdx.x;
    const int b    = blockIdx.x & (BN - 1);   // blockIdx = g*64 + b
    const int g    = blockIdx.x >> 6;
    const int lane = t & 63, wave = t >> 6;
    const int tr   = t & 3;                   // compute: col chunk (128 cols)
    const int irow = (g << 7) + (t >> 2);     // compute: owned output row
    const int u    = t - 512;                 // sync: owned exchange word

    if (t < TN) xs_l[t] = xs[b * TN + t];
    if (t < SN) se_l[t] = __uint_as_float(smax[t]) * (0.125f / 889.0f); // Kq/(127*7)

    const float c  = 1.0f / 512.0f;
    const float Kq = 0.125f;

    const int4* __restrict__ Epb = (const int4*)Epk;
    int4 e[4];
    float ESv = 0.0f;
    float outv = 0.0f;   // producer's own-row fp32 alpha (survives the loop)

    if (t < 512) {
        // prefetch E, ES for step 0 (symbol straight from global)
        const int s0 = xs[b * TN];
        const int4* Ep = Epb + (size_t)(s0 * 16 + tr * 4) * 512 + irow;
        #pragma unroll
        for (int k = 0; k < 4; ++k) e[k] = Ep[(size_t)k * 512];
        if (tr == 0) ESv = ES[(s0 << 9) + irow];
    }
    // initial alpha: threads t<128 own 4 rows each, computed redundantly
    float4 a0v = make_float4(0.f, 0.f, 0.f, 0.f);
    if (t < 128) {
        const float4 iw = ((const float4*)init_w)[t];
        a0v.x = expf(iw.x); a0v.y = expf(iw.y); a0v.z = expf(iw.z); a0v.w = expf(iw.w);
        float p = (a0v.x + a0v.y) + (a0v.z + a0v.w);   // 4-lane group = 16 rows = slot t>>2
        p += __shfl_xor(p, 1, 64);
        p += __shfl_xor(p, 2, 64);
        if ((t & 3) == 0) sws[0][t >> 2] = p;          // slot (g,w) layout: t>>2 = g*8+w
    }
    barrier_lds();
    float m_cur, m_prev;
    {
        float m0 = 0.0f;
        #pragma unroll
        for (int i = 0; i < 32; ++i) m0 += sws[0][i];  // fixed order everywhere
        m_cur = m0; m_prev = m0;
    }
    if (t < 128) {
        const float mu0    = m_cur * (1.0f / 512.0f);
        const float inv_sa = 127.0f / (Kq * mu0);
        const int q0 = (int)rintf(fminf(fmaxf((a0v.x - mu0) * inv_sa, -127.0f), 127.0f));
        const int q1 = (int)rintf(fminf(fmaxf((a0v.y - mu0) * inv_sa, -127.0f), 127.0f));
        const int q2 = (int)rintf(fminf(fmaxf((a0v.z - mu0) * inv_sa, -127.0f), 127.0f));
        const int q3 = (int)rintf(fminf(fmaxf((a0v.w - mu0) * inv_sa, -127.0f), 127.0f));
        ((int*)qa)[t] = (q0 & 255) | ((q1 & 255) << 8) | ((q2 & 255) << 16) | ((q3 & 255) << 24);
    }
    barrier_lds();

    for (int step = 0; step < TN; ++step) {
        const int par = step & 1;
        // m update: every thread, fixed order, broadcast LDS reads (~40cy).
        // At step 0, sws[0] holds the init partials -> same formula works.
        {
            float mn = 0.0f;
            #pragma unroll
            for (int i = 0; i < 32; ++i) mn += sws[par][i];
            m_prev = m_cur; m_cur = mn;
        }
        if (t < 512) {
            const int s      = xs_l[step];
            const int s_next = xs_l[(step + 1) & (TN - 1)];  // wraps: dummy at end
            const float beta = m_prev * (1.0f / 512.0f);     // alpha_t baseline
            // dots on prefetched int4 E(s) vs qa[par]; re-issue e for s_next
            const int4* qp  = (const int4*)qa[par];
            const int4* Epn = Epb + (size_t)(s_next * 16 + tr * 4) * 512 + irow;
            int d0 = 0, d1 = 0, d2 = 0, d3 = 0;
            #pragma unroll
            for (int k4 = 0; k4 < 4; ++k4) {
                const int4 E4  = e[k4];
                e[k4] = Epn[(size_t)k4 * 512];
                const int4 qlo = qp[2 * (4 * tr + k4) + 0];
                const int4 qhi = qp[2 * (4 * tr + k4) + 1];
                d0 = SDOT4(NIB_LO(E4.x), qlo.x, d0);
                d1 = SDOT4(NIB_HI(E4.x), qhi.x, d1);
                d2 = SDOT4(NIB_LO(E4.y), qlo.y, d2);
                d3 = SDOT4(NIB_HI(E4.y), qhi.y, d3);
                d0 = SDOT4(NIB_LO(E4.z), qlo.z, d0);
                d1 = SDOT4(NIB_HI(E4.z), qhi.z, d1);
                d2 = SDOT4(NIB_LO(E4.w), qlo.w, d2);
                d3 = SDOT4(NIB_HI(E4.w), qhi.w, d3);
            }
            __builtin_amdgcn_sched_barrier(0);   // pin E issue before publish
            int acc = (d0 + d1) + (d2 + d3);
            acc += __shfl_xor(acc, 1, 64);       // reduce over tr (lane bits 0..1)
            acc += __shfl_xor(acc, 2, 64);
            int q8 = 0;
            if (tr == 0) {
                outv = c * m_cur + beta * (ESv + se_l[s] * (float)acc);
                ESv = ES[(s_next << 9) + irow];  // prefetch next ES
                // producer-side quantize vs mu_t = m_cur/512 (known NOW;
                // next step's beta equals this -> consistent baseline)
                const float inv_sa = 127.0f / (Kq * (m_cur * (1.0f / 512.0f)));
                q8 = (int)rintf(fminf(fmaxf((outv - m_cur * (1.0f / 512.0f)) * inv_sa,
                                            -127.0f), 127.0f));
            }
            // pack 4 rows/word: owner lanes 0,4,..,60; byte = (lane>>2)&3
            unsigned v = (unsigned)(q8 & 255) << (8 * ((lane >> 2) & 3));
            v |= (unsigned)__shfl_xor((int)v, 4, 64);
            v |= (unsigned)__shfl_xor((int)v, 8, 64);
            const ull tag = (ull)(unsigned)(step + 1) << 32;
            ull* axp = ax + (size_t)((par ^ 1) * BN + b) * AXW;
            if ((lane & 15) == 0)                       // 4 alpha words / wave
                st_tag(axp + (g * 32 + wave * 4 + (lane >> 4)), tag | (ull)v);
            float ws = wave_sum(tr == 0 ? outv : 0.0f); // exact fp32 wave partial
            if (lane == 0)                              // 1 S word / wave
                st_tag(axp + (128 + g * 8 + wave), tag | (ull)(unsigned)__float_as_uint(ws));
        } else if (u < 160) {
            // sync: poll ONE word (vmcnt-clean wave); copy payload on arrival
            const unsigned want = (unsigned)(step + 1);
            const ull* ap = ax + (size_t)((par ^ 1) * BN + b) * AXW + u;
            ull a = ld_tag(ap);
            int gd = 0;
            while ((unsigned)(a >> 32) < want && ++gd < POLL_GUARD) {
                __builtin_amdgcn_s_sleep(1);
                a = ld_tag(ap);
            }
            if (u < 128) ((int*)qa)[(par ^ 1) * 128 + u] = (int)(unsigned)a;
            else         sws[par ^ 1][u - 128] = __uint_as_float((unsigned)a);
        }
        barrier_lds();   // single barrier: qa[par^1] + sws[par^1] ready
    }

    // finalize: producers hold fp32 alpha_T for their rows in outv
    {
        float fv = 0.0f;
        if (t < 512) {
            if (tr == 0) fv = outv * expf(fin_w[irow]);
            float ws = wave_sum(fv);
            if (lane == 0) sws[0][wave] = ws;   // loop done; safe to reuse
        }
        barrier_lds();
        if (t == 0) {
            float Fg = 0.0f;
            #pragma unroll
            for (int w = 0; w < 8; ++w) Fg += sws[0][w];
            st_tag(ax + (size_t)b * AXW + 160 + g,
                   ((ull)(unsigned)(TN + 1) << 32) | (ull)(unsigned)__float_as_uint(Fg));
        }
        if (g == 0 && t == 512) {
            const ull* fp = ax + (size_t)b * AXW + 160;
            ull f0 = ld_tag(fp + 0), f1 = ld_tag(fp + 1);
            ull f2 = ld_tag(fp + 2), f3 = ld_tag(fp + 3);
            int gd = 0;
            while ((((unsigned)(f0 >> 32) < (unsigned)(TN + 1)) |
                    ((unsigned)(f1 >> 32) < (unsigned)(TN + 1)) |
                    ((unsigned)(f2 >> 32) < (unsigned)(TN + 1)) |
                    ((unsigned)(f3 >> 32) < (unsigned)(TN + 1))) && ++gd < POLL_GUARD) {
                __builtin_amdgcn_s_sleep(1);
                f0 = ld_tag(fp + 0); f1 = ld_tag(fp + 1);
                f2 = ld_tag(fp + 2); f3 = ld_tag(fp + 3);
            }
            const float tot = (__uint_as_float((unsigned)f0) + __uint_as_float((unsigned)f1)) +
                              (__uint_as_float((unsigned)f2) + __uint_as_float((unsigned)f3));
            out[b] = logf(tot);
        }
    }
}

extern "C" void kernel_launch(void* const* d_in, const int* in_sizes, int n_in,
                              void* d_out, int out_size, void* d_ws, size_t ws_size,
                              hipStream_t stream) {
    const float* A      = (const float*)d_in[0];   // (Q, S, Q) fp32 log-weights
    const float* init_w = (const float*)d_in[1];   // (Q,)
    const float* fin_w  = (const float*)d_in[2];   // (Q,)
    const int*   xs     = (const int*)d_in[3];     // (B, T) int32
    float* out = (float*)d_out;                    // (B,) fp32

    char* ws = (char*)d_ws;
    int*      Epk  = (int*)ws;                                         // 8 MiB (int4 nibbles)
    float*    ES   = (float*)(ws + (8u << 20));                        // 128 KiB
    unsigned* smax = (unsigned*)(ws + (8u << 20) + (128u << 10));      // 1 KiB slot
    ull*      ax   = (ull*)(ws + (8u << 20) + (129u << 10));           // 2*64*164*8 = 164 KiB

    // tags reset every launch (proven protocol: LLC/HBM write-through
    // transport + memset + 'tag >= want' compare)
    hipMemsetAsync(smax, 0, (1u << 10) + (176u << 10), stream);
    k_minmax<<<512, 256, 0, stream>>>(A, smax);
    k_quant<<<512, 256, 0, stream>>>(A, smax, Epk, ES);
    k_fsa<<<GS * BN, 1024, 0, stream>>>(Epk, ES, smax, init_w, fin_w, xs, ax, out);
}

// Round 10
// 694.592 us; speedup vs baseline: 2.8918x; 1.1931x over previous
//
#include <hip/hip_runtime.h>

// Problem constants (from reference): Q=512 states, S=64 symbols, B=64, T=256.
#define QN 512
#define SN 64
#define BN 64
#define TN 256
#define GS 4   // row-split: blocks per batch (grid = GS*BN = 256 blocks -> 1/CU)

typedef unsigned long long ull;

// ---- int8 dot4 (v_dot4_i32_i8) with software fallback ----
#if defined(__has_builtin)
#if __has_builtin(__builtin_amdgcn_sdot4)
#define SDOT4(a, b, c) __builtin_amdgcn_sdot4((a), (b), (c), false)
#endif
#endif
#ifndef SDOT4
static __device__ __forceinline__ int sdot4_sw(int a, int b, int c) {
    c += (int)(signed char)(a)       * (int)(signed char)(b);
    c += (int)(signed char)(a >> 8)  * (int)(signed char)(b >> 8);
    c += (int)(signed char)(a >> 16) * (int)(signed char)(b >> 16);
    c += (int)(signed char)(a >> 24) * (int)(signed char)(b >> 24);
    return c;
}
#define SDOT4(a, b, c) sdot4_sw((a), (b), (c))
#endif

// signed-nibble unpack: bytes of (x & 0x0F..) are in [0,15]; ^8 then -8 per
// byte maps to [-8,7] two's-complement bytes; no cross-byte borrow possible.
#define NIB_LO(x) ((((x) & 0x0F0F0F0F) ^ 0x08080808) - 0x08080808)
#define NIB_HI(x) (((((x) >> 4) & 0x0F0F0F0F) ^ 0x08080808) - 0x08080808)

static __device__ __forceinline__ float wave_sum(float v) {
    #pragma unroll
    for (int o = 32; o > 0; o >>= 1) v += __shfl_xor(v, o, 64);
    return v;
}
static __device__ __forceinline__ float wave_max(float v) {
    #pragma unroll
    for (int o = 32; o > 0; o >>= 1) v = fmaxf(v, __shfl_xor(v, o, 64));
    return v;
}

// Barrier with LDS-only drain: waits lgkmcnt(0) but leaves global loads in
// flight (vmcnt untouched) so cross-step register prefetch survives the
// barrier. imm encoding (gfx9/CDNA): vm[3:0]=0xF, exp[6:4]=7, lgkm[11:8]=0,
// vm[15:14]=3 -> 0xC07F.
static __device__ __forceinline__ void barrier_lds(void) {
    __builtin_amdgcn_s_waitcnt(0xC07F);
    __builtin_amdgcn_s_barrier();
}

// ---- Exchange transport ----
// PUBLISH via atomic swap (fire-and-forget): atomic RMWs execute AT the
// coherence point (LLC) -- the line stays dirty in LLC instead of writing
// through to HBM (round-8 counter evidence: plain agent stores showed up
// 1:1 in WRITE_SIZE => HBM write-through => ~1us visibility). POLL via
// agent-scope atomic load (reads the LLC copy). Round-2: flat/lgkm polling
// unsound. Round-6: sc0-only L2 exchange unsound cross-XCD.
static __device__ __forceinline__ void st_tag(ull* p, ull v) {
    (void)__hip_atomic_exchange(p, v, __ATOMIC_RELAXED, __HIP_MEMORY_SCOPE_AGENT);
}
static __device__ __forceinline__ ull ld_tag(const ull* p) {
    return __hip_atomic_load(p, __ATOMIC_RELAXED, __HIP_MEMORY_SCOPE_AGENT);
}

#define POLL_GUARD (1 << 20)   // protocol error -> visible wrong answer, not hang

// ---- Kernel A: per-symbol bound of |E| = |exp(A) - 1/Q| via min/max of A ----
__global__ __launch_bounds__(256) void k_minmax(const float* __restrict__ A,
                                                unsigned* __restrict__ smax) {
    const int s  = blockIdx.x >> 3;
    const int i0 = (blockIdx.x & 7) * 64;
    const int tl = threadIdx.x & 127;
    const int rh = threadIdx.x >> 7;
    float mx = -1e30f, mn = 1e30f;
    for (int ro = 0; ro < 64; ro += 2) {
        const int i = i0 + ro + rh;
        float4 a4 = ((const float4*)A)[(size_t)(i * 64 + s) * 128 + tl];
        mx = fmaxf(mx, fmaxf(fmaxf(a4.x, a4.y), fmaxf(a4.z, a4.w)));
        mn = fminf(mn, fminf(fminf(a4.x, a4.y), fminf(a4.z, a4.w)));
    }
    mx = wave_max(mx);
    mn = -wave_max(-mn);
    if ((threadIdx.x & 63) == 0) {
        const float c = 1.0f / 512.0f;
        float se = fmaxf(expf(mx) - c, c - expf(mn));
        atomicMax(&smax[s], __float_as_uint(se));
    }
}

// ---- Kernel B: quantize E to int4 nibbles + EXACT fp32 rowsums ----
// Epk (int4-vector units): (s*16 + j32)*512 + i covers the 32-column block
// j = 32*j32 + {0..31} at output row i: word w's LO nibbles are cols
// 32*j32+4w+{0..3}, HI nibbles are cols 32*j32+16+4w+{0..3}.
// ES[s][i] = sum_j E[i,j] in fp32 (exact): the mean-term of the int4
// quantization error cancels against it, leaving only error x alpha-deviation.
__global__ __launch_bounds__(256) void k_quant(const float* __restrict__ A,
                                               const unsigned* __restrict__ smax,
                                               int* __restrict__ Epk,
                                               float* __restrict__ ES) {
    __shared__ int tile[64][129];   // int8 bytes of e4 values in [-7,7]
    __shared__ float fsum[64];
    const int s  = blockIdx.x >> 3;
    const int i0 = (blockIdx.x & 7) * 64;
    const float se  = __uint_as_float(smax[s]);
    const float inv = se > 0.0f ? 7.0f / se : 0.0f;   // int4 grid: se4 = se/7
    const float c = 1.0f / 512.0f;
    const int tl = threadIdx.x & 127;
    const int rh = threadIdx.x >> 7;
    if (threadIdx.x < 64) fsum[threadIdx.x] = 0.0f;
    __syncthreads();
    for (int ro = 0; ro < 64; ro += 2) {
        const int r = ro + rh;
        const int i = i0 + r;
        float4 a4 = ((const float4*)A)[(size_t)(i * 64 + s) * 128 + tl];
        const float e0 = expf(a4.x) - c, e1 = expf(a4.y) - c;
        const float e2 = expf(a4.z) - c, e3 = expf(a4.w) - c;
        int q0 = (int)rintf(fminf(fmaxf(e0 * inv, -7.0f), 7.0f));
        int q1 = (int)rintf(fminf(fmaxf(e1 * inv, -7.0f), 7.0f));
        int q2 = (int)rintf(fminf(fmaxf(e2 * inv, -7.0f), 7.0f));
        int q3 = (int)rintf(fminf(fmaxf(e3 * inv, -7.0f), 7.0f));
        tile[r][tl] = (q0 & 255) | ((q1 & 255) << 8) | ((q2 & 255) << 16) | ((q3 & 255) << 24);
        // exact fp32 rowsum of E (each wave covers half a row's columns)
        float ws = wave_sum(e0 + e1 + e2 + e3);
        if ((threadIdx.x & 63) == 0) atomicAdd(&fsum[r], ws);
    }
    __syncthreads();
    if (threadIdx.x < 64) ES[(s << 9) + i0 + threadIdx.x] = fsum[threadIdx.x];
    // pack nibble pairs (col j with col j+16 of the same 32-block) and write
    const int il = threadIdx.x & 63;
    const int jg = threadIdx.x >> 6;          // 0..3
    for (int jo = 0; jo < 4; ++jo) {
        const int j32 = jg * 4 + jo;
        int4 v;
        v.x = (tile[il][8 * j32 + 0] & 0x0F0F0F0F) | ((tile[il][8 * j32 + 4] & 0x0F0F0F0F) << 4);
        v.y = (tile[il][8 * j32 + 1] & 0x0F0F0F0F) | ((tile[il][8 * j32 + 5] & 0x0F0F0F0F) << 4);
        v.z = (tile[il][8 * j32 + 2] & 0x0F0F0F0F) | ((tile[il][8 * j32 + 6] & 0x0F0F0F0F) << 4);
        v.w = (tile[il][8 * j32 + 3] & 0x0F0F0F0F) | ((tile[il][8 * j32 + 7] & 0x0F0F0F0F) << 4);
        ((int4*)Epk)[((size_t)(s * 16 + j32) * 512) + i0 + il] = v;
    }
}

// ---- Main kernel: round-4 structure (proven 570us) + 2 memory-path fixes ----
// (1) blockIdx = b*GS + g  =>  XCD x (blockIdx%8) hosts ONLY g = x%4. Block
//     g's E working set (rows [128g,128g+128) over all 64 symbols) is 2 MiB
//     int4 -> fully resident in the XCD's 4 MiB L2. E-reads leave the
//     LLC/HBM path (read-only data: pure perf heuristic, no coherence risk).
// (2) publishes use atomic swap -> exchange lines live in the LLC, not HBM.
// Everything else identical to round 4: compute thread t<512 (row irow =
// g*128 + t>>2, col-chunk tr = t&3, 4 int4 E-frags), sync thread t>=512 owns
// ONE alpha word (vmcnt-clean poll), qa/mb parity double-buffered, tags
// step+1 with '>=' + memset, producer lead bounded to 1 step.
__global__ __launch_bounds__(1024) void k_fsa(const int* __restrict__ Epk,
                                              const float* __restrict__ ES,
                                              const unsigned* __restrict__ smax,
                                              const float* __restrict__ init_w,
                                              const float* __restrict__ fin_w,
                                              const int* __restrict__ xs,
                                              ull* __restrict__ ax,   // [2][BN][QN] tagged alpha
                                              float* __restrict__ out) {
    __shared__ __align__(16) int qa[2][QN / 4];   // int8 alpha, parity buffers
    __shared__ int   xs_l[TN];
    __shared__ float wsum[8];
    __shared__ float se_l[SN];
    __shared__ float mb[2];                       // block sum m, parity buffers

    const int t    = threadIdx.x;
    const int b    = blockIdx.x >> 2;         // blockIdx = b*GS + g (XCD slab map)
    const int g    = blockIdx.x & (GS - 1);
    const int lane = t & 63, wave = t >> 6;
    const int tr   = t & 3;                   // compute: col chunk (128 cols)
    const int irow = (g << 7) + (t >> 2);     // compute: owned output row
    const int u    = t - 512;                 // sync: owned alpha index

    if (t < TN) xs_l[t] = xs[b * TN + t];
    if (t < SN) se_l[t] = __uint_as_float(smax[t]) * (0.125f / 889.0f); // Kq/(127*7)

    const float c  = 1.0f / 512.0f;
    const float Kq = 0.125f;

    const int4* __restrict__ Epb = (const int4*)Epk;
    int4 e[4];
    float ESv = 0.0f;
    float av = 0.0f;   // sync: gathered alpha value

    if (t < 512) {
        // prefetch E, ES for step 0 (symbol straight from global)
        const int s0 = xs[b * TN];
        const int4* Ep = Epb + (size_t)(s0 * 16 + tr * 4) * 512 + irow;
        #pragma unroll
        for (int k = 0; k < 4; ++k) e[k] = Ep[(size_t)k * 512];
        if (tr == 0) ESv = ES[(s0 << 9) + irow];
    } else {
        // initial alpha: one element per sync thread, computed redundantly
        av = expf(init_w[u]);
        float ws = wave_sum(av);
        if (lane == 0) wsum[wave - 8] = ws;
    }
    barrier_lds();
    if (t >= 512) {
        float m0 = 0.0f;
        #pragma unroll
        for (int w = 0; w < 8; ++w) m0 += wsum[w];
        const float mu     = m0 * (1.0f / 512.0f);
        const float inv_sa = 127.0f / (Kq * mu);
        const int q = (int)rintf(fminf(fmaxf((av - mu) * inv_sa, -127.0f), 127.0f));
        ((char*)qa)[u] = (char)q;             // parity-0 buffer, byte u
        if (u == 0) mb[0] = m0;
    }
    barrier_lds();

    for (int step = 0; step < TN; ++step) {
        const int p = step & 1;
        if (t < 512) {
            const int s_next = xs_l[(step + 1) & (TN - 1)];  // wraps: dummy at end
            const float mm   = mb[p];
            // dots on prefetched int4 E(s); re-issue each e-slot for s_next
            const int4* qp  = (const int4*)qa[p];
            const int4* Epn = Epb + (size_t)(s_next * 16 + tr * 4) * 512 + irow;
            int acc0 = 0, acc1 = 0, acc2 = 0, acc3 = 0;
            #pragma unroll
            for (int k = 0; k < 4; ++k) {
                const int4 E4  = e[k];
                e[k] = Epn[(size_t)k * 512];
                const int4 qlo = qp[2 * (4 * tr + k) + 0];   // cols 32j+0..15
                const int4 qhi = qp[2 * (4 * tr + k) + 1];   // cols 32j+16..31
                acc0 = SDOT4(NIB_LO(E4.x), qlo.x, acc0);
                acc1 = SDOT4(NIB_HI(E4.x), qhi.x, acc1);
                acc2 = SDOT4(NIB_LO(E4.y), qlo.y, acc2);
                acc3 = SDOT4(NIB_HI(E4.y), qhi.y, acc3);
                acc0 = SDOT4(NIB_LO(E4.z), qlo.z, acc0);
                acc1 = SDOT4(NIB_HI(E4.z), qhi.z, acc1);
                acc2 = SDOT4(NIB_LO(E4.w), qlo.w, acc2);
                acc3 = SDOT4(NIB_HI(E4.w), qhi.w, acc3);
            }
            __builtin_amdgcn_sched_barrier(0);   // pin E issue before publish
            int acc = (acc0 + acc1) + (acc2 + acc3);
            acc += __shfl_xor(acc, 1, 64);       // reduce over tr (lane bits 0..1)
            acc += __shfl_xor(acc, 2, 64);
            if (tr == 0) {
                const int s     = xs_l[step];
                const float ESc = ESv;
                ESv = ES[(s_next << 9) + irow];  // prefetch next ES
                const float mu = mm * (1.0f / 512.0f);
                const float outv = c * mm + mu * (ESc + se_l[s] * (float)acc);
                st_tag(ax + (size_t)(((p ^ 1)) * BN + b) * QN + irow,
                       ((ull)(unsigned)(step + 1) << 32) | (ull)__float_as_uint(outv));
            }
        } else {
            // gather step+1 (parity p^1): poll own word; retries are cheap
            // (this wave's vmcnt queue contains nothing else)
            const unsigned want = (unsigned)(step + 1);
            const ull* ap = ax + (size_t)((p ^ 1) * BN + b) * QN + u;
            ull a = ld_tag(ap);
            int gd = 0;
            while ((unsigned)(a >> 32) < want && ++gd < POLL_GUARD) {
                __builtin_amdgcn_s_sleep(1);
                a = ld_tag(ap);
            }
            av = __uint_as_float((unsigned)a);
            float ws = wave_sum(av);
            if (lane == 0) wsum[wave - 8] = ws;
        }
        barrier_lds();   // barrier1: wsum ready; dots done (qa[p] free next iter)

        if (t >= 512) {
            float m = 0.0f;
            #pragma unroll
            for (int w = 0; w < 8; ++w) m += wsum[w];    // same tree in all blocks
            const float mu     = m * (1.0f / 512.0f);
            const float inv_sa = 127.0f / (Kq * mu);
            const int q = (int)rintf(fminf(fmaxf((av - mu) * inv_sa, -127.0f), 127.0f));
            ((char*)qa)[(p ^ 1) * QN + u] = (char)q;
            if (u == 0) mb[p ^ 1] = m;
        }
        barrier_lds();   // barrier2: qa[p^1] + mb[p^1] ready for next step
    }

    // finalize: sync threads hold gathered final alpha (tag 256) in av
    {
        float v = 0.0f;
        if (t >= 512) {
            v = av * expf(fin_w[u]);
            float ws = wave_sum(v);
            if (lane == 0) wsum[wave - 8] = ws;
        }
        barrier_lds();
        if (g == 0 && t == 512) {
            float tot = 0.0f;
            #pragma unroll
            for (int w = 0; w < 8; ++w) tot += wsum[w];
            out[b] = logf(tot);
        }
    }
}

extern "C" void kernel_launch(void* const* d_in, const int* in_sizes, int n_in,
                              void* d_out, int out_size, void* d_ws, size_t ws_size,
                              hipStream_t stream) {
    const float* A      = (const float*)d_in[0];   // (Q, S, Q) fp32 log-weights
    const float* init_w = (const float*)d_in[1];   // (Q,)
    const float* fin_w  = (const float*)d_in[2];   // (Q,)
    const int*   xs     = (const int*)d_in[3];     // (B, T) int32
    float* out = (float*)d_out;                    // (B,) fp32

    char* ws = (char*)d_ws;
    int*      Epk  = (int*)ws;                                          // 8 MiB (int4 nibbles)
    float*    ES   = (float*)(ws + (8u << 20));                         // 128 KiB fp32 rowsums
    unsigned* smax = (unsigned*)(ws + (8u << 20) + (128u << 10));       // 1 KiB slot
    ull*      ax   = (ull*)(ws + (8u << 20) + (129u << 10));            // 512 KiB

    // tags must reset every launch ('tag >= want' protocol). Atomic-swap
    // writes land at the LLC; memset re-zeroes the backing memory and the
    // first swap of the new launch re-dirties the line -- '>= ' compare is
    // monotone within a launch, so ordering vs the memset is safe (tag 1..256
    // always exceeds 0, and stale high tags are cleared by the memset which
    // is coherent with LLC at kernel-launch boundaries).
    hipMemsetAsync(smax, 0, (1u << 10) + (512u << 10), stream);
    k_minmax<<<512, 256, 0, stream>>>(A, smax);
    k_quant<<<512, 256, 0, stream>>>(A, smax, Epk, ES);
    k_fsa<<<GS * BN, 1024, 0, stream>>>(Epk, ES, smax, init_w, fin_w, xs, ax, out);
}

// Round 11
// 669.493 us; speedup vs baseline: 3.0002x; 1.0375x over previous
//
#include <hip/hip_runtime.h>

// Problem constants (from reference): Q=512 states, S=64 symbols, B=64, T=256.
#define QN 512
#define SN 64
#define BN 64
#define TN 256
#define GS 4   // row/col-split: blocks per batch (grid = GS*BN = 256 blocks)

typedef unsigned long long ull;

// ---- int8 dot4 (v_dot4_i32_i8) with software fallback ----
#if defined(__has_builtin)
#if __has_builtin(__builtin_amdgcn_sdot4)
#define SDOT4(a, b, c) __builtin_amdgcn_sdot4((a), (b), (c), false)
#endif
#endif
#ifndef SDOT4
static __device__ __forceinline__ int sdot4_sw(int a, int b, int c) {
    c += (int)(signed char)(a)       * (int)(signed char)(b);
    c += (int)(signed char)(a >> 8)  * (int)(signed char)(b >> 8);
    c += (int)(signed char)(a >> 16) * (int)(signed char)(b >> 16);
    c += (int)(signed char)(a >> 24) * (int)(signed char)(b >> 24);
    return c;
}
#define SDOT4(a, b, c) sdot4_sw((a), (b), (c))
#endif

// signed-nibble unpack: bytes of (x & 0x0F..) are in [0,15]; ^8 then -8 per
// byte maps to [-8,7] two's-complement bytes; no cross-byte borrow possible.
#define NIB_LO(x) ((((x) & 0x0F0F0F0F) ^ 0x08080808) - 0x08080808)
#define NIB_HI(x) (((((x) >> 4) & 0x0F0F0F0F) ^ 0x08080808) - 0x08080808)

static __device__ __forceinline__ float wave_sum(float v) {
    #pragma unroll
    for (int o = 32; o > 0; o >>= 1) v += __shfl_xor(v, o, 64);
    return v;
}
static __device__ __forceinline__ float wave_max(float v) {
    #pragma unroll
    for (int o = 32; o > 0; o >>= 1) v = fmaxf(v, __shfl_xor(v, o, 64));
    return v;
}

// Barrier with LDS-only drain: waits lgkmcnt(0) but leaves global loads in
// flight (vmcnt untouched) so cross-step register prefetch survives the
// barrier. imm encoding (gfx9/CDNA): vm[3:0]=0xF, exp[6:4]=7, lgkm[11:8]=0,
// vm[15:14]=3 -> 0xC07F.
static __device__ __forceinline__ void barrier_lds(void) {
    __builtin_amdgcn_s_waitcnt(0xC07F);
    __builtin_amdgcn_s_barrier();
}

// Exchange transport: agent-scope atomics (sc0 sc1). PROVEN rounds 1/3/4/7.
// Session ledger: r2 flat/lgkm polling unsound (lgkm decrement != data
// return); r6 sc0-only L2 exchange unsound cross-XCD (clean stale lines, no
// invalidation); r8 exchange traffic is HBM-backed (volume matters); r9
// thin-exchange null (latency floor, not width); r10 atomic-swap transport
// null. This plain store + poll is the best-known transport.
static __device__ __forceinline__ void st_tag(ull* p, ull v) {
    __hip_atomic_store(p, v, __ATOMIC_RELAXED, __HIP_MEMORY_SCOPE_AGENT);
}
static __device__ __forceinline__ ull ld_tag(const ull* p) {
    return __hip_atomic_load(p, __ATOMIC_RELAXED, __HIP_MEMORY_SCOPE_AGENT);
}

#define POLL_GUARD (1 << 20)   // protocol error -> visible wrong answer, not hang

// ---- Fused prep kernel: minmax + per-symbol phase sync + int4 quantize ----
// Replaces k_minmax + k_quant (saves one launch AND the second 64 MB A-stream:
// phase 2 re-reads this block's 128 KiB A-slice L2-warm). Per-symbol sync:
// the 8 contributor blocks atomicMax(smax[s]) -> threadfence -> atomicAdd
// (cnt[s]); a scout polls cnt[s]==8 with acquire (proven agent-atomic
// machinery), then reads the final smax. 512 blocks x 256 thr are trivially
// co-resident -> the poll cannot deadlock (guarded anyway).
__global__ __launch_bounds__(256) void k_prep(const float* __restrict__ A,
                                              unsigned* __restrict__ smax,
                                              unsigned* __restrict__ cnt,
                                              int* __restrict__ Epk,
                                              float* __restrict__ ES,
                                              float* __restrict__ CS) {
    __shared__ int tile[64][129];     // int8 bytes of e4 values in [-7,7]
    __shared__ float fsumC[64][GS];   // per-row per-chunk exact sums
    __shared__ float wmx[4], wmn[4];
    __shared__ float se_sh;
    const int s  = blockIdx.x >> 3;
    const int i0 = (blockIdx.x & 7) * 64;
    const int tl = threadIdx.x & 127;
    const int rh = threadIdx.x >> 7;
    const float c = 1.0f / 512.0f;

    // ---- phase 1: min/max over our 64-row slice (warms L2 for phase 2) ----
    float mx = -1e30f, mn = 1e30f;
    for (int ro = 0; ro < 64; ro += 2) {
        const int i = i0 + ro + rh;
        float4 a4 = ((const float4*)A)[(size_t)(i * 64 + s) * 128 + tl];
        mx = fmaxf(mx, fmaxf(fmaxf(a4.x, a4.y), fmaxf(a4.z, a4.w)));
        mn = fminf(mn, fminf(fminf(a4.x, a4.y), fminf(a4.z, a4.w)));
    }
    mx = wave_max(mx);
    mn = -wave_max(-mn);
    if ((threadIdx.x & 63) == 0) { wmx[threadIdx.x >> 6] = mx; wmn[threadIdx.x >> 6] = mn; }
    if (threadIdx.x < 256) ((float*)fsumC)[threadIdx.x] = 0.0f;   // 64*GS = 256
    __syncthreads();
    if (threadIdx.x == 0) {
        const float bmx = fmaxf(fmaxf(wmx[0], wmx[1]), fmaxf(wmx[2], wmx[3]));
        const float bmn = fminf(fminf(wmn[0], wmn[1]), fminf(wmn[2], wmn[3]));
        const float se = fmaxf(expf(bmx) - c, c - expf(bmn));
        atomicMax(&smax[s], __float_as_uint(se));   // device-scope
        __threadfence();                            // max visible before count
        atomicAdd(&cnt[s], 1u);
        unsigned v = __hip_atomic_load(&cnt[s], __ATOMIC_ACQUIRE, __HIP_MEMORY_SCOPE_AGENT);
        int gd = 0;
        while (v < 8u && ++gd < POLL_GUARD) {
            __builtin_amdgcn_s_sleep(1);
            v = __hip_atomic_load(&cnt[s], __ATOMIC_ACQUIRE, __HIP_MEMORY_SCOPE_AGENT);
        }
        se_sh = __uint_as_float(
            __hip_atomic_load(&smax[s], __ATOMIC_RELAXED, __HIP_MEMORY_SCOPE_AGENT));
    }
    __syncthreads();
    const float se  = se_sh;
    const float inv = se > 0.0f ? 7.0f / se : 0.0f;   // int4 grid: se4 = se/7

    // ---- phase 2: quantize to int4 + exact per-chunk fp32 rowsums ----
    for (int ro = 0; ro < 64; ro += 2) {
        const int r = ro + rh;
        const int i = i0 + r;
        float4 a4 = ((const float4*)A)[(size_t)(i * 64 + s) * 128 + tl];
        const float e0 = expf(a4.x) - c, e1 = expf(a4.y) - c;
        const float e2 = expf(a4.z) - c, e3 = expf(a4.w) - c;
        int q0 = (int)rintf(fminf(fmaxf(e0 * inv, -7.0f), 7.0f));
        int q1 = (int)rintf(fminf(fmaxf(e1 * inv, -7.0f), 7.0f));
        int q2 = (int)rintf(fminf(fmaxf(e2 * inv, -7.0f), 7.0f));
        int q3 = (int)rintf(fminf(fmaxf(e3 * inv, -7.0f), 7.0f));
        tile[r][tl] = (q0 & 255) | ((q1 & 255) << 8) | ((q2 & 255) << 16) | ((q3 & 255) << 24);
        // exact fp32 per-chunk rowsum: 32-lane group = one 128-col chunk
        float gs = e0 + e1 + e2 + e3;
        #pragma unroll
        for (int o = 16; o > 0; o >>= 1) gs += __shfl_xor(gs, o, 64);
        if ((threadIdx.x & 31) == 0) atomicAdd(&fsumC[r][tl >> 5], gs);
    }
    __syncthreads();
    if (threadIdx.x < 256) {
        const int r = threadIdx.x >> 2, gg = threadIdx.x & 3;
        CS[((size_t)(s * GS + gg) << 9) + i0 + r] = fsumC[r][gg];
    }
    if (threadIdx.x < 64) {
        const int r = threadIdx.x;
        ES[(s << 9) + i0 + r] = (fsumC[r][0] + fsumC[r][1]) + (fsumC[r][2] + fsumC[r][3]);
    }
    // pack nibble pairs (col j with col j+16 of the same 32-block) and write
    const int il = threadIdx.x & 63;
    const int jg = threadIdx.x >> 6;          // 0..3
    for (int jo = 0; jo < 4; ++jo) {
        const int j32 = jg * 4 + jo;
        int4 v;
        v.x = (tile[il][8 * j32 + 0] & 0x0F0F0F0F) | ((tile[il][8 * j32 + 4] & 0x0F0F0F0F) << 4);
        v.y = (tile[il][8 * j32 + 1] & 0x0F0F0F0F) | ((tile[il][8 * j32 + 5] & 0x0F0F0F0F) << 4);
        v.z = (tile[il][8 * j32 + 2] & 0x0F0F0F0F) | ((tile[il][8 * j32 + 6] & 0x0F0F0F0F) << 4);
        v.w = (tile[il][8 * j32 + 3] & 0x0F0F0F0F) | ((tile[il][8 * j32 + 7] & 0x0F0F0F0F) << 4);
        ((int4*)Epk)[((size_t)(s * 16 + j32) * 512) + i0 + il] = v;
    }
}

// ---- Main kernel: round-7 structure (best: 549us) + XCD slab mapping ----
// blockIdx = b*GS + g  =>  XCD x (blockIdx%8) hosts only g = x%4. Block g's
// E working set (phase R rows [128g,128g+128) x all symbols = 2 MiB, phase C
// cols [128g,128g+128) x all symbols = 0.5 MiB) fits the XCD's 4 MiB L2
// (r10 counter-proved the residency effect: FETCH 585->141 MB). Read-only
// data -> pure perf heuristic, no coherence exposure (unlike r6).
// Super-step k: s_R = xs[2k] ROW-split (own 128 rows, kept LOCAL in fp32);
// s_C = xs[2k+1] COLUMN-split (quantize own chunk vs known mu_{2k}, publish
// full-512-row partial y_g). ONE exchange per 2 steps. Transport: LLC tagged
// words, tag = k+1, '>=' + memset (proven). Producer lead bounded to 1
// super-step -> parity double-buffer overwrite-safe. 256 blocks co-resident.
__global__ __launch_bounds__(1024) void k_fsa(const int* __restrict__ Epk,
                                              const float* __restrict__ ES,
                                              const float* __restrict__ CS,
                                              const unsigned* __restrict__ smax,
                                              const float* __restrict__ init_w,
                                              const float* __restrict__ fin_w,
                                              const int* __restrict__ xs,
                                              ull* __restrict__ ax,   // [2][BN][GS][QN] tagged y
                                              float* __restrict__ out) {
    __shared__ __align__(16) int qa[2][QN / 4];    // int8 alpha (full), parity
    __shared__ __align__(16) int qloc[QN / 16];    // int8 chunk quant (128 B)
    __shared__ int   xs_l[TN];
    __shared__ float wsum[8];                      // sync-wave partials (m)
    __shared__ float sws[8];                       // compute-wave partials (S_g)
    __shared__ float se_l[SN];
    __shared__ float mb[2];                        // block sum m, parity

    const int t    = threadIdx.x;
    const int b    = blockIdx.x >> 2;         // blockIdx = b*GS + g (XCD slab map)
    const int g    = blockIdx.x & (GS - 1);
    const int lane = t & 63, wave = t >> 6;
    const int tr   = t & 3;                   // phase R: col chunk
    const int lr   = t >> 2;                  // phase R: local row 0..127
    const int irow = (g << 7) + lr;           // phase R: owned output row
    const int u    = t - 512;                 // sync: owned alpha index

    if (t < TN) xs_l[t] = xs[b * TN + t];
    if (t < SN) se_l[t] = __uint_as_float(smax[t]) * (0.125f / 889.0f); // Kq/(127*7)

    const float c  = 1.0f / 512.0f;
    const float Kq = 0.125f;

    const int4* __restrict__ Epb = (const int4*)Epk;
    int4 eR[4], eC[4];
    float ESv = 0.0f, CSv = 0.0f;
    float av = 0.0f;   // sync: gathered alpha value

    if (t < 512) {
        // prefetch both phases of super-step 0 (symbols straight from global)
        const int s0 = xs[b * TN], s1 = xs[b * TN + 1];
        const int4* EpR = Epb + (size_t)(s0 * 16 + tr * 4) * 512 + irow;
        const int4* EpC = Epb + (size_t)(s1 * 16 + g * 4) * 512 + t;
        #pragma unroll
        for (int k = 0; k < 4; ++k) { eR[k] = EpR[(size_t)k * 512]; eC[k] = EpC[(size_t)k * 512]; }
        if (tr == 0) ESv = ES[(s0 << 9) + irow];
        CSv = CS[((size_t)(s1 * GS + g) << 9) + t];
    } else {
        // initial alpha: one element per sync thread, computed redundantly
        av = expf(init_w[u]);
        float ws = wave_sum(av);
        if (lane == 0) wsum[wave - 8] = ws;
    }
    barrier_lds();
    if (t >= 512) {
        float m0 = 0.0f;
        #pragma unroll
        for (int w = 0; w < 8; ++w) m0 += wsum[w];
        const float mu     = m0 * (1.0f / 512.0f);
        const float inv_sa = 127.0f / (Kq * mu);
        const int q = (int)rintf(fminf(fmaxf((av - mu) * inv_sa, -127.0f), 127.0f));
        ((char*)qa)[u] = (char)q;             // parity-0 buffer, byte u
        if (u == 0) mb[0] = m0;
    }
    barrier_lds();

    for (int k = 0; k < TN / 2; ++k) {
        const int par = k & 1;
        float mu = 0.0f;
        if (t < 512) {
            const int sR  = xs_l[2 * k];
            const int sRn = xs_l[(2 * k + 2) & (TN - 1)];   // wraps: dummy at end
            const float mm = mb[par];
            mu = mm * (1.0f / 512.0f);
            // ---- phase R: rows [128g,128g+128) of alpha_{2k+1} ----
            const int4* qp   = (const int4*)qa[par];
            const int4* EpRn = Epb + (size_t)(sRn * 16 + tr * 4) * 512 + irow;
            int a0 = 0, a1 = 0, a2 = 0, a3 = 0;
            #pragma unroll
            for (int k4 = 0; k4 < 4; ++k4) {
                const int4 E4 = eR[k4];
                eR[k4] = EpRn[(size_t)k4 * 512];
                const int4 qlo = qp[2 * (4 * tr + k4) + 0];
                const int4 qhi = qp[2 * (4 * tr + k4) + 1];
                a0 = SDOT4(NIB_LO(E4.x), qlo.x, a0);
                a1 = SDOT4(NIB_HI(E4.x), qhi.x, a1);
                a2 = SDOT4(NIB_LO(E4.y), qlo.y, a2);
                a3 = SDOT4(NIB_HI(E4.y), qhi.y, a3);
                a0 = SDOT4(NIB_LO(E4.z), qlo.z, a0);
                a1 = SDOT4(NIB_HI(E4.z), qhi.z, a1);
                a2 = SDOT4(NIB_LO(E4.w), qlo.w, a2);
                a3 = SDOT4(NIB_HI(E4.w), qhi.w, a3);
            }
            __builtin_amdgcn_sched_barrier(0);   // pin eR re-issue before the rest
            int acc = (a0 + a1) + (a2 + a3);
            acc += __shfl_xor(acc, 1, 64);       // reduce over tr (lane bits 0..1)
            acc += __shfl_xor(acc, 2, 64);
            float outv = 0.0f;
            if (tr == 0) {
                outv = c * mm + mu * (ESv + se_l[sR] * (float)acc);
                ESv = ES[(sRn << 9) + irow];     // prefetch next ES
                // quantize own chunk vs mu_{2k} (deviation ~0.2% mu << Kq=12.5%)
                const float inv_sa = 127.0f / (Kq * mu);
                const int q8 = (int)rintf(fminf(fmaxf((outv - mu) * inv_sa, -127.0f), 127.0f));
                ((char*)qloc)[lr] = (char)q8;
            }
            float ws = wave_sum(outv);           // S_g partial (non-tr0 lanes add 0)
            if (lane == 0) sws[wave] = ws;
        }
        barrier_lds();   // A: qloc + sws visible (intra-block only -- no exchange!)

        if (t < 512) {
            const int sC  = xs_l[2 * k + 1];
            const int sCn = xs_l[(2 * k + 3) & (TN - 1)];
            float Sg = 0.0f;
            #pragma unroll
            for (int w = 0; w < 8; ++w) Sg += sws[w];
            // ---- phase C: full-512-row partial over column chunk g ----
            const int4* qc   = (const int4*)qloc;
            const int4* EpCn = Epb + (size_t)(sCn * 16 + g * 4) * 512 + t;
            int a0 = 0, a1 = 0, a2 = 0, a3 = 0;
            #pragma unroll
            for (int k4 = 0; k4 < 4; ++k4) {
                const int4 E4 = eC[k4];
                eC[k4] = EpCn[(size_t)k4 * 512];
                const int4 ql = qc[2 * k4 + 0];   // local cols 32k4+4w+{0..3}
                const int4 qh = qc[2 * k4 + 1];   // local cols 32k4+16+4w+{0..3}
                a0 = SDOT4(NIB_LO(E4.x), ql.x, a0);
                a1 = SDOT4(NIB_HI(E4.x), qh.x, a1);
                a2 = SDOT4(NIB_LO(E4.y), ql.y, a2);
                a3 = SDOT4(NIB_HI(E4.y), qh.y, a3);
                a0 = SDOT4(NIB_LO(E4.z), ql.z, a0);
                a1 = SDOT4(NIB_HI(E4.z), qh.z, a1);
                a2 = SDOT4(NIB_LO(E4.w), ql.w, a2);
                a3 = SDOT4(NIB_HI(E4.w), qh.w, a3);
            }
            __builtin_amdgcn_sched_barrier(0);
            const int accC = (a0 + a1) + (a2 + a3);
            // y_g[i] = c*S_g + mu*(CS_g[i] + se*acc)  (exact mean terms)
            const float y = c * Sg + mu * (CSv + se_l[sC] * (float)accC);
            CSv = CS[((size_t)(sCn * GS + g) << 9) + t];   // prefetch next CS
            st_tag(ax + ((size_t)((par ^ 1) * BN + b) * GS + g) * QN + t,
                   ((ull)(unsigned)(k + 1) << 32) | (ull)__float_as_uint(y));
        } else {
            // gather: poll the 4 sibling partials for own row u, sum them
            const unsigned want = (unsigned)(k + 1);
            const ull* ap = ax + (size_t)((par ^ 1) * BN + b) * GS * QN + u;
            ull w0 = ld_tag(ap + 0 * QN);
            ull w1 = ld_tag(ap + 1 * QN);
            ull w2 = ld_tag(ap + 2 * QN);
            ull w3 = ld_tag(ap + 3 * QN);
            int gd = 0;
            while ((((unsigned)(w0 >> 32) < want) | ((unsigned)(w1 >> 32) < want) |
                    ((unsigned)(w2 >> 32) < want) | ((unsigned)(w3 >> 32) < want)) &&
                   ++gd < POLL_GUARD) {
                __builtin_amdgcn_s_sleep(1);
                w0 = ld_tag(ap + 0 * QN);
                w1 = ld_tag(ap + 1 * QN);
                w2 = ld_tag(ap + 2 * QN);
                w3 = ld_tag(ap + 3 * QN);
            }
            // fixed order -> bitwise identical across all blocks
            av = (__uint_as_float((unsigned)w0) + __uint_as_float((unsigned)w1)) +
                 (__uint_as_float((unsigned)w2) + __uint_as_float((unsigned)w3));
            float ws = wave_sum(av);
            if (lane == 0) wsum[wave - 8] = ws;
        }
        barrier_lds();   // 1: wsum visible

        if (t >= 512) {
            float m = 0.0f;
            #pragma unroll
            for (int w = 0; w < 8; ++w) m += wsum[w];    // same tree in all blocks
            const float mu2    = m * (1.0f / 512.0f);
            const float inv_sa = 127.0f / (Kq * mu2);
            const int q = (int)rintf(fminf(fmaxf((av - mu2) * inv_sa, -127.0f), 127.0f));
            ((char*)qa)[(par ^ 1) * QN + u] = (char)q;
            if (u == 0) mb[par ^ 1] = m;
        }
        barrier_lds();   // 2: qa[par^1] + mb[par^1] ready for next super-step
    }

    // finalize: sync threads hold gathered final alpha (tag 128) in av
    {
        float v = 0.0f;
        if (t >= 512) {
            v = av * expf(fin_w[u]);
            float ws = wave_sum(v);
            if (lane == 0) wsum[wave - 8] = ws;
        }
        barrier_lds();
        if (g == 0 && t == 512) {
            float tot = 0.0f;
            #pragma unroll
            for (int w = 0; w < 8; ++w) tot += wsum[w];
            out[b] = logf(tot);
        }
    }
}

extern "C" void kernel_launch(void* const* d_in, const int* in_sizes, int n_in,
                              void* d_out, int out_size, void* d_ws, size_t ws_size,
                              hipStream_t stream) {
    const float* A      = (const float*)d_in[0];   // (Q, S, Q) fp32 log-weights
    const float* init_w = (const float*)d_in[1];   // (Q,)
    const float* fin_w  = (const float*)d_in[2];   // (Q,)
    const int*   xs     = (const int*)d_in[3];     // (B, T) int32
    float* out = (float*)d_out;                    // (B,) fp32

    char* ws = (char*)d_ws;
    int*      Epk  = (int*)ws;                                         // 8 MiB (int4 nibbles)
    float*    ES   = (float*)(ws + (8u << 20));                        // 128 KiB
    float*    CS   = (float*)(ws + (8u << 20) + (128u << 10));         // 512 KiB
    unsigned* smax = (unsigned*)(ws + (8u << 20) + (640u << 10));      // 1 KiB slot
    unsigned* cnt  = (unsigned*)(ws + (8u << 20) + (641u << 10));      // 1 KiB slot
    ull*      ax   = (ull*)(ws + (8u << 20) + (642u << 10));           // 2 MiB

    // smax/cnt/ax reset every launch (contiguous). Proven protocol: LLC
    // transport + memset + 'tag >= want' compare.
    hipMemsetAsync(smax, 0, (2u << 10) + (2u << 20), stream);
    k_prep<<<512, 256, 0, stream>>>(A, smax, cnt, Epk, ES, CS);
    k_fsa<<<GS * BN, 1024, 0, stream>>>(Epk, ES, CS, smax, init_w, fin_w, xs, ax, out);
}